// Round 16
// baseline (214.764 us; speedup 1.0000x reference)
//
#include <hip/hip_runtime.h>
#include <hip/hip_bf16.h>

#define Tq 4096
#define Cdim 1024
#define NH 16
#define DH 64

typedef __attribute__((ext_vector_type(8))) short short8;
typedef __attribute__((ext_vector_type(4))) float f32x4;

#define SCLQ 0.1803368801111204f   // (1/sqrt(64)) * log2(e), folded into Q

__device__ __forceinline__ unsigned short f2bf(float f) {
  union { float f; unsigned int u; } v; v.f = f;
  unsigned int r = v.u + 0x7FFFu + ((v.u >> 16) & 1u);
  return (unsigned short)(r >> 16);
}

__device__ __forceinline__ float bf2f(unsigned short u) {
  union { unsigned int u; float f; } v; v.u = ((unsigned int)u) << 16;
  return v.f;
}

__device__ __forceinline__ unsigned int cvtpk_bf16(float lo, float hi) {
  unsigned int r;
  asm volatile("v_cvt_pk_bf16_f32 %0, %1, %2" : "=v"(r) : "v"(lo), "v"(hi));
  return r;
}

// ---------------- fp32 -> bf16 convert ----------------
__global__ void cvt_kernel(const float* __restrict__ in, unsigned short* __restrict__ out, int n) {
  int idx = (blockIdx.x * blockDim.x + threadIdx.x) * 4;
  if (idx + 3 < n) {
    float4 v = *reinterpret_cast<const float4*>(in + idx);
    ushort4 o;
    o.x = f2bf(v.x); o.y = f2bf(v.y); o.z = f2bf(v.z); o.w = f2bf(v.w);
    *reinterpret_cast<ushort4*>(out + idx) = o;
  }
}

// ------------- transpose + convert: in[R][C] f32 -> out[C][R] bf16 -------------
__global__ void transpose_cvt(const float* __restrict__ in, unsigned short* __restrict__ out,
                              int R, int Ccols) {
  __shared__ float tile[64][65];
  int c0 = blockIdx.x * 64, r0 = blockIdx.y * 64;
  int tx = threadIdx.x & 63;
  int ty = threadIdx.x >> 6;   // 0..3
  #pragma unroll
  for (int rr = 0; rr < 64; rr += 4)
    tile[rr + ty][tx] = in[(r0 + rr + ty) * Ccols + c0 + tx];
  __syncthreads();
  #pragma unroll
  for (int rr = 0; rr < 64; rr += 4)
    out[(c0 + rr + ty) * R + r0 + tx] = f2bf(tile[tx][rr + ty]);
}

// ------------- GEMM: C[M][N] = A[M][K](bf16) * B^T[N][K](bf16) -------------
// m97 structure: linear LDS + global_load_lds width-16, 2 barriers/K-step.
// OUT_MODE 0 additionally pre-scales the Q section by SCLQ (softmax fold).
template<int OUT_MODE>
__global__ __launch_bounds__(256, 3)
void gemm_bt(const unsigned short* __restrict__ A,
             const unsigned short* __restrict__ B,
             void* __restrict__ Cout,
             int M, int N, int K)
{
  __shared__ __align__(16) unsigned short As[128][64];
  __shared__ __align__(16) unsigned short Bs[128][64];
  const int tid = threadIdx.x;
  const int lane = tid & 63;
  const int wave = tid >> 6;
  const int wm = wave >> 1, wn = wave & 1;

  // XCD swizzle (gridDim.x % 8 == 0 guaranteed by launch config)
  const int chunk = gridDim.x >> 3;
  const int b = blockIdx.x;
  const int swz = (b & 7) * chunk + (b >> 3);
  const int n0 = (swz >> 5) * 128;   // 32 M-blocks per column panel (M=4096)
  const int m0 = (swz & 31) * 128;

  f32x4 acc[4][4] = {};

  const int lrow = lane >> 3;        // 0..7 (row within one 1KB wave deposit)
  const int lcol = (lane & 7) * 8;   // ushort col within 64

  for (int k0 = 0; k0 < K; k0 += 64) {
    __syncthreads();
    #pragma unroll
    for (int t = 0; t < 4; ++t) {
      const int r = wave * 32 + t * 8;
      __builtin_amdgcn_global_load_lds(
        (const __attribute__((address_space(1))) void*)&A[(size_t)(m0 + r + lrow) * K + k0 + lcol],
        (__attribute__((address_space(3))) void*)&As[r][0], 16, 0, 0);
      __builtin_amdgcn_global_load_lds(
        (const __attribute__((address_space(1))) void*)&B[(size_t)(n0 + r + lrow) * K + k0 + lcol],
        (__attribute__((address_space(3))) void*)&Bs[r][0], 16, 0, 0);
    }
    __syncthreads();
    #pragma unroll
    for (int kk = 0; kk < 64; kk += 32) {
      const int frow = lane & 15;
      const int fcol = kk + 8 * (lane >> 4);
      short8 a[4], bfr[4];
      #pragma unroll
      for (int i = 0; i < 4; ++i) {
        a[i]   = *reinterpret_cast<const short8*>(&As[wm * 64 + i * 16 + frow][fcol]);
        bfr[i] = *reinterpret_cast<const short8*>(&Bs[wn * 64 + i * 16 + frow][fcol]);
      }
      #pragma unroll
      for (int i = 0; i < 4; ++i)
        #pragma unroll
        for (int j = 0; j < 4; ++j)
          acc[i][j] = __builtin_amdgcn_mfma_f32_16x16x32_bf16(a[i], bfr[j], acc[i][j], 0, 0, 0);
    }
  }

  const int rbase = (lane >> 4) * 4;
  const int ccol = lane & 15;
  #pragma unroll
  for (int i = 0; i < 4; ++i) {
    const int row0 = m0 + wm * 64 + i * 16 + rbase;
    #pragma unroll
    for (int j = 0; j < 4; ++j) {
      const int col = n0 + wn * 64 + j * 16 + ccol;
      if (OUT_MODE == 0) {
        unsigned short* q = (unsigned short*)Cout;
        int sec = col >> 10, rem = col & 1023;
        int hh = rem >> 6, d = rem & 63;
        if (sec == 2) {
          ushort4 pk;
          pk.x = f2bf(acc[i][j][0]); pk.y = f2bf(acc[i][j][1]);
          pk.z = f2bf(acc[i][j][2]); pk.w = f2bf(acc[i][j][3]);
          *reinterpret_cast<ushort4*>(
              &q[((size_t)(2 * NH + hh) * DH + d) * Tq + row0]) = pk;
        } else {
          const float mult = (sec == 0) ? SCLQ : 1.0f;   // fold softmax scale into Q
          #pragma unroll
          for (int r = 0; r < 4; ++r)
            q[(((size_t)sec * NH + hh) * Tq + row0 + r) * DH + d] = f2bf(acc[i][j][r] * mult);
        }
      } else {
        #pragma unroll
        for (int r = 0; r < 4; ++r)
          ((float*)Cout)[(row0 + r) * N + col] = acc[i][j][r];
      }
    }
  }
}

// ------------- flash attention, KV split-K=3: causal + dense prefix -------------
// QBLK=128: 4 waves x 32 q-rows (two 16-row sets SHARE K/V fragment reads --
// r6's verified mechanism), 256 threads. Split s takes 128-kv tiles t=s,s+3,...
// (r12's verified infra: LPT heavy-first + backfill). Q pre-scaled ->
// p = exp2(s) direct. Strides 72/136 (36/68 dw == 4 mod 32, b128-optimal).
// grid 1536 = 16h x 32qc x 3s; 4 blocks/CU -> 1024 resident + 512 backfill.
__global__ __launch_bounds__(256, 4)
void attn_kernel(const unsigned short* __restrict__ qkv,   // Q[h][t][d],K[h][t][d],VT[h][d][t]
                 unsigned short* __restrict__ po01,        // [2][16][4096][64] bf16 (d_out)
                 unsigned short* __restrict__ po2,         // [16][4096][64] bf16 (ws)
                 float* __restrict__ pl,                   // [3][16][4096] f32
                 const int* __restrict__ nf_ptr)
{
  __shared__ __align__(16) unsigned short Ks[128][72];
  __shared__ __align__(16) unsigned short VTs[64][136];

  const int tid  = threadIdx.x;
  const int lane = tid & 63;
  const int w    = tid >> 6;           // 0..3
  const int g    = lane >> 4;          // 0..3
  const int li   = lane & 15;

  // grid 1536: h = b&15; bb = b>>4 (0..95); s = bb%3; qc = 31 - bb/3 (LPT)
  const int h   = blockIdx.x & 15;
  const int bb  = blockIdx.x >> 4;
  const int s   = bb % 3;
  const int qc  = 31 - bb / 3;
  const int q0  = qc * 128;
  const int nf  = nf_ptr[0];

  const unsigned short* Qh  = qkv + (size_t)h * Tq * DH;
  const unsigned short* Kh  = qkv + (size_t)(NH + h) * Tq * DH;
  const unsigned short* VTh = qkv + (size_t)(2 * NH + h) * DH * Tq;

  // Q fragments: two 16-row sets per wave; col = li = q-row within set
  int qrow[2];
  qrow[0] = q0 + w * 32 + li;
  qrow[1] = qrow[0] + 16;
  short8 qf[2][2];
  #pragma unroll
  for (int r0 = 0; r0 < 2; ++r0)
    #pragma unroll
    for (int kk = 0; kk < 2; ++kk)
      qf[r0][kk] = *reinterpret_cast<const short8*>(
          &Qh[qrow[r0] * DH + kk * 32 + 8 * g]);

  f32x4 o[2][4] = {};
  f32x4 ol[2] = {};

  short8 ones;
  #pragma unroll
  for (int e = 0; e < 8; ++e) ones[e] = (short)0x3F80;   // bf16 1.0

  int lastt = q0 + 127;
  if (nf - 1 > lastt) lastt = nf - 1;
  const int T = (lastt >> 7) + 1;      // number of 128-wide KV tiles for this chunk

  // staging thread mapping (256 threads, 4 segs each for K and VT)
  const int krow0 = tid >> 3;           // 0..31 (+32j)
  const int kcol  = (tid & 7) * 8;
  const int vrow0 = tid >> 4;           // 0..15 (+16j)
  const int vcol  = (tid & 15) * 8;

  // prologue: stage this split's first tile (kv = s*128; in-bounds for all s)
  {
    const int nx = s * 128;
    short8 nk[4], nv[4];
    #pragma unroll
    for (int j = 0; j < 4; ++j) {
      nk[j] = *reinterpret_cast<const short8*>(&Kh[(nx + krow0 + 32 * j) * DH + kcol]);
      nv[j] = *reinterpret_cast<const short8*>(&VTh[(size_t)(vrow0 + 16 * j) * Tq + nx + vcol]);
    }
    #pragma unroll
    for (int j = 0; j < 4; ++j) {
      *reinterpret_cast<short8*>(&Ks[krow0 + 32 * j][kcol]) = nk[j];
      *reinterpret_cast<short8*>(&VTs[vrow0 + 16 * j][vcol]) = nv[j];
    }
  }
  __syncthreads();

  for (int t = s; t < T; t += 3) {
    const int kv0 = t * 128;
    const bool havenext = (t + 3 < T);
    // T14: issue next tile's global loads now; they fly during compute
    short8 nk[4], nv[4];
    if (havenext) {
      const int nx = kv0 + 384;
      #pragma unroll
      for (int j = 0; j < 4; ++j) {
        nk[j] = *reinterpret_cast<const short8*>(&Kh[(nx + krow0 + 32 * j) * DH + kcol]);
        nv[j] = *reinterpret_cast<const short8*>(&VTh[(size_t)(vrow0 + 16 * j) * Tq + nx + vcol]);
      }
    }

    // two 64-kv halves; K/V fragments read ONCE per half, shared by both row sets
    #pragma unroll
    for (int h2 = 0; h2 < 2; ++h2) {
      const int kvb = kv0 + h2 * 64;

      // K fragments (shared)
      short8 kf[4][2];
      #pragma unroll
      for (int nb = 0; nb < 4; ++nb)
        #pragma unroll
        for (int kk = 0; kk < 2; ++kk)
          kf[nb][kk] = *reinterpret_cast<const short8*>(
              &Ks[h2 * 64 + nb * 16 + li][kk * 32 + 8 * g]);

      short8 W[2][2];   // PV B-fragments for each row set

      #pragma unroll
      for (int r0 = 0; r0 < 2; ++r0) {
        // S^T = K · Q^T (already exp2-domain via pre-scaled Q)
        f32x4 sarr[4];
        __builtin_amdgcn_s_setprio(1);
        #pragma unroll
        for (int nb = 0; nb < 4; ++nb) {
          f32x4 a = {};
          #pragma unroll
          for (int kk = 0; kk < 2; ++kk)
            a = __builtin_amdgcn_mfma_f32_16x16x32_bf16(kf[nb][kk], qf[r0][kk], a, 0, 0, 0);
          sarr[nb] = a;
        }
        __builtin_amdgcn_s_setprio(0);

        // mask + direct exp2 (no offset: o/l invariant to constant scaling)
        const bool needmask = !((kvb + 63 <= q0 + w * 32 + r0 * 16) || (kvb + 63 < nf));
        float p[4][4];
        #pragma unroll
        for (int nb = 0; nb < 4; ++nb) {
          #pragma unroll
          for (int r = 0; r < 4; ++r) {
            float v = sarr[nb][r];
            if (needmask) {
              const int kvi = kvb + nb * 16 + 4 * g + r;
              if (!(kvi <= qrow[r0] || kvi < nf)) v = -1e30f;
            }
            p[nb][r] = exp2f(v);
          }
        }

        // pack + permlane 4x4 word transpose -> PV B-fragments
        #pragma unroll
        for (int kk = 0; kk < 2; ++kk) {
          unsigned int X1 = cvtpk_bf16(p[2 * kk][0], p[2 * kk][1]);
          unsigned int X2 = cvtpk_bf16(p[2 * kk][2], p[2 * kk][3]);
          unsigned int Y1 = cvtpk_bf16(p[2 * kk + 1][0], p[2 * kk + 1][1]);
          unsigned int Y2 = cvtpk_bf16(p[2 * kk + 1][2], p[2 * kk + 1][3]);
          asm volatile("v_permlane32_swap_b32 %0, %1" : "+v"(X1), "+v"(Y1));
          asm volatile("v_permlane32_swap_b32 %0, %1" : "+v"(X2), "+v"(Y2));
          asm volatile("v_permlane16_swap_b32 %0, %1" : "+v"(X1), "+v"(Y1));
          asm volatile("v_permlane16_swap_b32 %0, %1" : "+v"(X2), "+v"(Y2));
          union { unsigned int u[4]; short8 s8; } Wt;
          Wt.u[0] = X1; Wt.u[1] = X2; Wt.u[2] = Y1; Wt.u[3] = Y2;
          W[r0][kk] = Wt.s8;
        }
      }

      // V fragments read ONCE, shared by both row sets
      __builtin_amdgcn_s_setprio(1);
      #pragma unroll
      for (int kk = 0; kk < 2; ++kk) {
        #pragma unroll
        for (int db = 0; db < 4; ++db) {
          short8 vb = *reinterpret_cast<const short8*>(
              &VTs[db * 16 + li][h2 * 64 + kk * 32 + 8 * g]);
          #pragma unroll
          for (int r0 = 0; r0 < 2; ++r0)
            o[r0][db] = __builtin_amdgcn_mfma_f32_16x16x32_bf16(vb, W[r0][kk], o[r0][db], 0, 0, 0);
        }
        #pragma unroll
        for (int r0 = 0; r0 < 2; ++r0)
          ol[r0] = __builtin_amdgcn_mfma_f32_16x16x32_bf16(ones, W[r0][kk], ol[r0], 0, 0, 0);
      }
      __builtin_amdgcn_s_setprio(0);
    }

    if (havenext) {
      __syncthreads();   // all waves done reading current tile
      #pragma unroll
      for (int j = 0; j < 4; ++j) {
        *reinterpret_cast<short8*>(&Ks[krow0 + 32 * j][kcol]) = nk[j];
        *reinterpret_cast<short8*>(&VTs[vrow0 + 16 * j][vcol]) = nv[j];
      }
      __syncthreads();   // new tile visible
    }
  }

  // epilogue: write UNNORMALIZED partial O (bf16) + partial l (f32), both sets
  #pragma unroll
  for (int r0 = 0; r0 < 2; ++r0) {
    unsigned short* pp = (s == 2 ? po2 : po01 + (size_t)s * NH * Tq * DH)
                         + ((size_t)h * Tq + qrow[r0]) * DH;
    #pragma unroll
    for (int db = 0; db < 4; ++db) {
      ushort4 pk;
      pk.x = f2bf(o[r0][db][0]);
      pk.y = f2bf(o[r0][db][1]);
      pk.z = f2bf(o[r0][db][2]);
      pk.w = f2bf(o[r0][db][3]);
      *reinterpret_cast<ushort4*>(&pp[db * 16 + 4 * g]) = pk;
    }
    if (g == 0)
      pl[((size_t)s * NH + h) * Tq + qrow[r0]] = ol[r0][0];
  }
}

// ------------- merge split partials: ybf = (po0+po1+po2)/(l0+l1+l2) -------------
__global__ __launch_bounds__(256)
void merge_kernel(const unsigned short* __restrict__ po01,  // [2][16][4096][64] bf16
                  const unsigned short* __restrict__ po2,   // [16][4096][64] bf16
                  const float* __restrict__ pl,             // [3][16][4096] f32
                  unsigned short* __restrict__ ybf)         // [4096][1024] bf16
{
  const int idx = blockIdx.x * 256 + threadIdx.x;  // 524288 total (one per 8 d-elems)
  const int d8  = idx & 7;
  const int row = (idx >> 3) & 4095;
  const int h   = idx >> 15;
  const size_t base = ((size_t)h * Tq + row) * DH + d8 * 8;
  short8 a = *reinterpret_cast<const short8*>(&po01[base]);
  short8 b = *reinterpret_cast<const short8*>(&po01[(size_t)NH * Tq * DH + base]);
  short8 c = *reinterpret_cast<const short8*>(&po2[base]);
  const float l0 = pl[(size_t)h * Tq + row];
  const float l1 = pl[((size_t)NH + h) * Tq + row];
  const float l2 = pl[((size_t)2 * NH + h) * Tq + row];
  const float inv = 1.0f / (l0 + l1 + l2);
  short8 outv;
  #pragma unroll
  for (int j = 0; j < 8; ++j) {
    float v = (bf2f((unsigned short)a[j]) + bf2f((unsigned short)b[j])
               + bf2f((unsigned short)c[j])) * inv;
    outv[j] = (short)f2bf(v);
  }
  *reinterpret_cast<short8*>(&ybf[(size_t)row * Cdim + h * DH + d8 * 8]) = outv;
}

extern "C" void kernel_launch(void* const* d_in, const int* in_sizes, int n_in,
                              void* d_out, int out_size, void* d_ws, size_t ws_size,
                              hipStream_t stream) {
  (void)in_sizes; (void)n_in; (void)out_size; (void)ws_size;
  const float* x  = (const float*)d_in[0];
  const float* wa = (const float*)d_in[1];
  const float* wp = (const float*)d_in[2];
  const int*   nf = (const int*)d_in[3];
  float* out = (float*)d_out;

  char* ws = (char*)d_ws;
  unsigned short* x_bf = (unsigned short*)(ws);                              // 8 MiB (dead after gemm<0>)
  unsigned short* waT  = (unsigned short*)(ws + (size_t)8  * 1024 * 1024);   // 6 MiB (dead after gemm<0>)
  unsigned short* wpT  = (unsigned short*)(ws + (size_t)14 * 1024 * 1024);   // 2 MiB
  unsigned short* qkvb = (unsigned short*)(ws + (size_t)16 * 1024 * 1024);   // 24 MiB
  unsigned short* ybf  = (unsigned short*)(ws + (size_t)40 * 1024 * 1024);   // 8 MiB

  // split-K partials: po0/po1 in d_out (16 MiB, fully rewritten by gemm<1>);
  // pl (768 KiB) at ws+0 and po2 (8 MiB) at ws+1MiB, overlaying the dead
  // x_bf/waT regions (attn runs strictly after gemm<0>).
  unsigned short* po01 = (unsigned short*)d_out;
  float* pl = (float*)(ws);
  unsigned short* po2 = (unsigned short*)(ws + (size_t)1 * 1024 * 1024);

  cvt_kernel<<<4096, 256, 0, stream>>>(x, x_bf, Tq * Cdim);
  transpose_cvt<<<dim3(48, 16), 256, 0, stream>>>(wa, waT, 1024, 3072);
  transpose_cvt<<<dim3(16, 16), 256, 0, stream>>>(wp, wpT, 1024, 1024);
  gemm_bt<0><<<768, 256, 0, stream>>>(x_bf, waT, (void*)qkvb, Tq, 3 * Cdim, Cdim);
  attn_kernel<<<1536, 256, 0, stream>>>(qkvb, po01, po2, pl, nf);
  merge_kernel<<<2048, 256, 0, stream>>>(po01, po2, pl, ybf);
  gemm_bt<1><<<256, 256, 0, stream>>>(ybf, wpT, (void*)out, Tq, Cdim, Cdim);
}

// Round 17
// 149.824 us; speedup vs baseline: 1.4334x; 1.4334x over previous
//
#include <hip/hip_runtime.h>
#include <hip/hip_bf16.h>

#define Tq 4096
#define Cdim 1024
#define NH 16
#define DH 64

typedef __attribute__((ext_vector_type(8))) short short8;
typedef __attribute__((ext_vector_type(4))) float f32x4;

#define SCLQ 0.1803368801111204f   // (1/sqrt(64)) * log2(e), folded into Q

__device__ __forceinline__ unsigned short f2bf(float f) {
  union { float f; unsigned int u; } v; v.f = f;
  unsigned int r = v.u + 0x7FFFu + ((v.u >> 16) & 1u);
  return (unsigned short)(r >> 16);
}

__device__ __forceinline__ float bf2f(unsigned short u) {
  union { unsigned int u; float f; } v; v.u = ((unsigned int)u) << 16;
  return v.f;
}

__device__ __forceinline__ unsigned int cvtpk_bf16(float lo, float hi) {
  unsigned int r;
  asm volatile("v_cvt_pk_bf16_f32 %0, %1, %2" : "=v"(r) : "v"(lo), "v"(hi));
  return r;
}

// ---------------- fp32 -> bf16 convert ----------------
__global__ void cvt_kernel(const float* __restrict__ in, unsigned short* __restrict__ out, int n) {
  int idx = (blockIdx.x * blockDim.x + threadIdx.x) * 4;
  if (idx + 3 < n) {
    float4 v = *reinterpret_cast<const float4*>(in + idx);
    ushort4 o;
    o.x = f2bf(v.x); o.y = f2bf(v.y); o.z = f2bf(v.z); o.w = f2bf(v.w);
    *reinterpret_cast<ushort4*>(out + idx) = o;
  }
}

// ------------- transpose + convert: in[R][C] f32 -> out[C][R] bf16 -------------
__global__ void transpose_cvt(const float* __restrict__ in, unsigned short* __restrict__ out,
                              int R, int Ccols) {
  __shared__ float tile[64][65];
  int c0 = blockIdx.x * 64, r0 = blockIdx.y * 64;
  int tx = threadIdx.x & 63;
  int ty = threadIdx.x >> 6;   // 0..3
  #pragma unroll
  for (int rr = 0; rr < 64; rr += 4)
    tile[rr + ty][tx] = in[(r0 + rr + ty) * Ccols + c0 + tx];
  __syncthreads();
  #pragma unroll
  for (int rr = 0; rr < 64; rr += 4)
    out[(c0 + rr + ty) * R + r0 + tx] = f2bf(tile[tx][rr + ty]);
}

// ------------- GEMM: C[M][N] = A[M][K](bf16) * B^T[N][K](bf16) -------------
// m97 structure: linear LDS + global_load_lds width-16, 2 barriers/K-step.
// OUT_MODE 0 additionally pre-scales the Q section by SCLQ (softmax fold).
template<int OUT_MODE>
__global__ __launch_bounds__(256, 3)
void gemm_bt(const unsigned short* __restrict__ A,
             const unsigned short* __restrict__ B,
             void* __restrict__ Cout,
             int M, int N, int K)
{
  __shared__ __align__(16) unsigned short As[128][64];
  __shared__ __align__(16) unsigned short Bs[128][64];
  const int tid = threadIdx.x;
  const int lane = tid & 63;
  const int wave = tid >> 6;
  const int wm = wave >> 1, wn = wave & 1;

  // XCD swizzle (gridDim.x % 8 == 0 guaranteed by launch config)
  const int chunk = gridDim.x >> 3;
  const int b = blockIdx.x;
  const int swz = (b & 7) * chunk + (b >> 3);
  const int n0 = (swz >> 5) * 128;   // 32 M-blocks per column panel (M=4096)
  const int m0 = (swz & 31) * 128;

  f32x4 acc[4][4] = {};

  const int lrow = lane >> 3;        // 0..7 (row within one 1KB wave deposit)
  const int lcol = (lane & 7) * 8;   // ushort col within 64

  for (int k0 = 0; k0 < K; k0 += 64) {
    __syncthreads();
    #pragma unroll
    for (int t = 0; t < 4; ++t) {
      const int r = wave * 32 + t * 8;
      __builtin_amdgcn_global_load_lds(
        (const __attribute__((address_space(1))) void*)&A[(size_t)(m0 + r + lrow) * K + k0 + lcol],
        (__attribute__((address_space(3))) void*)&As[r][0], 16, 0, 0);
      __builtin_amdgcn_global_load_lds(
        (const __attribute__((address_space(1))) void*)&B[(size_t)(n0 + r + lrow) * K + k0 + lcol],
        (__attribute__((address_space(3))) void*)&Bs[r][0], 16, 0, 0);
    }
    __syncthreads();
    #pragma unroll
    for (int kk = 0; kk < 64; kk += 32) {
      const int frow = lane & 15;
      const int fcol = kk + 8 * (lane >> 4);
      short8 a[4], bfr[4];
      #pragma unroll
      for (int i = 0; i < 4; ++i) {
        a[i]   = *reinterpret_cast<const short8*>(&As[wm * 64 + i * 16 + frow][fcol]);
        bfr[i] = *reinterpret_cast<const short8*>(&Bs[wn * 64 + i * 16 + frow][fcol]);
      }
      #pragma unroll
      for (int i = 0; i < 4; ++i)
        #pragma unroll
        for (int j = 0; j < 4; ++j)
          acc[i][j] = __builtin_amdgcn_mfma_f32_16x16x32_bf16(a[i], bfr[j], acc[i][j], 0, 0, 0);
    }
  }

  const int rbase = (lane >> 4) * 4;
  const int ccol = lane & 15;
  #pragma unroll
  for (int i = 0; i < 4; ++i) {
    const int row0 = m0 + wm * 64 + i * 16 + rbase;
    #pragma unroll
    for (int j = 0; j < 4; ++j) {
      const int col = n0 + wn * 64 + j * 16 + ccol;
      if (OUT_MODE == 0) {
        unsigned short* q = (unsigned short*)Cout;
        int sec = col >> 10, rem = col & 1023;
        int hh = rem >> 6, d = rem & 63;
        if (sec == 2) {
          ushort4 pk;
          pk.x = f2bf(acc[i][j][0]); pk.y = f2bf(acc[i][j][1]);
          pk.z = f2bf(acc[i][j][2]); pk.w = f2bf(acc[i][j][3]);
          *reinterpret_cast<ushort4*>(
              &q[((size_t)(2 * NH + hh) * DH + d) * Tq + row0]) = pk;
        } else {
          const float mult = (sec == 0) ? SCLQ : 1.0f;   // fold softmax scale into Q
          #pragma unroll
          for (int r = 0; r < 4; ++r)
            q[(((size_t)sec * NH + hh) * Tq + row0 + r) * DH + d] = f2bf(acc[i][j][r] * mult);
        }
      } else {
        #pragma unroll
        for (int r = 0; r < 4; ++r)
          ((float*)Cout)[(row0 + r) * N + col] = acc[i][j][r];
      }
    }
  }
}

// ------------- flash attention, KV split-K=3: causal + dense prefix -------------
// QBLK=64, 4 waves x 16 q-rows, 256 threads. Split s takes kv-tiles t = s, s+3, ...
// Q pre-scaled -> p = exp2(s) directly. LDS strides 72/136 ushorts
// (36/68 dwords == 4 mod 32: the b128-optimal 16B-slot spread). This
// 4-block/CU, 52-VGPR config sits on the HW quanta: zero-LDS (r13),
// 64kv/8-block (r14), and shared-fragment QBLK=128 (r16) all falsified
// with spill/latency counter evidence.
__global__ __launch_bounds__(256, 4)
void attn_kernel(const unsigned short* __restrict__ qkv,   // Q[h][t][d],K[h][t][d],VT[h][d][t]
                 unsigned short* __restrict__ po01,        // [2][16][4096][64] bf16 (d_out)
                 unsigned short* __restrict__ po2,         // [16][4096][64] bf16 (ws)
                 float* __restrict__ pl,                   // [3][16][4096] f32
                 const int* __restrict__ nf_ptr)
{
  __shared__ __align__(16) unsigned short Ks[128][72];
  __shared__ __align__(16) unsigned short VTs[64][136];

  const int tid  = threadIdx.x;
  const int lane = tid & 63;
  const int w    = tid >> 6;           // 0..3
  const int g    = lane >> 4;          // 0..3
  const int li   = lane & 15;

  // grid 3072: h = b&15; s = (b>>4)%3; qc = 63 - (b>>4)/3  (heavy-first LPT)
  const int h   = blockIdx.x & 15;
  const int bb  = blockIdx.x >> 4;
  const int s   = bb % 3;
  const int qc  = 63 - bb / 3;
  const int q0  = qc * 64;
  const int nf  = nf_ptr[0];

  const unsigned short* Qh  = qkv + (size_t)h * Tq * DH;
  const unsigned short* Kh  = qkv + (size_t)(NH + h) * Tq * DH;
  const unsigned short* VTh = qkv + (size_t)(2 * NH + h) * DH * Tq;

  // Q fragments (B-operand of swapped QK^T): col = li = q-row
  const int qrow = q0 + w * 16 + li;
  short8 qf[2];
  #pragma unroll
  for (int kk = 0; kk < 2; ++kk)
    qf[kk] = *reinterpret_cast<const short8*>(&Qh[qrow * DH + kk * 32 + 8 * g]);

  f32x4 o[4] = {};
  f32x4 ol = {};

  short8 ones;
  #pragma unroll
  for (int e = 0; e < 8; ++e) ones[e] = (short)0x3F80;   // bf16 1.0

  int lastt = q0 + 63;
  if (nf - 1 > lastt) lastt = nf - 1;
  const int T = (lastt >> 7) + 1;      // number of 128-wide KV tiles for this chunk

  // staging thread mapping (256 threads, 4 segs each for K and VT)
  const int krow0 = tid >> 3;           // 0..31 (+32j)
  const int kcol  = (tid & 7) * 8;
  const int vrow0 = tid >> 4;           // 0..15 (+16j)
  const int vcol  = (tid & 15) * 8;

  // prologue: stage this split's first tile (kv = s*128; within bounds for all s)
  {
    const int nx = s * 128;
    short8 nk[4], nv[4];
    #pragma unroll
    for (int j = 0; j < 4; ++j) {
      nk[j] = *reinterpret_cast<const short8*>(&Kh[(nx + krow0 + 32 * j) * DH + kcol]);
      nv[j] = *reinterpret_cast<const short8*>(&VTh[(size_t)(vrow0 + 16 * j) * Tq + nx + vcol]);
    }
    #pragma unroll
    for (int j = 0; j < 4; ++j) {
      *reinterpret_cast<short8*>(&Ks[krow0 + 32 * j][kcol]) = nk[j];
      *reinterpret_cast<short8*>(&VTs[vrow0 + 16 * j][vcol]) = nv[j];
    }
  }
  __syncthreads();

  for (int t = s; t < T; t += 3) {
    const int kv0 = t * 128;
    const bool havenext = (t + 3 < T);
    // T14: issue next tile's global loads now; they fly during compute
    short8 nk[4], nv[4];
    if (havenext) {
      const int nx = kv0 + 384;
      #pragma unroll
      for (int j = 0; j < 4; ++j) {
        nk[j] = *reinterpret_cast<const short8*>(&Kh[(nx + krow0 + 32 * j) * DH + kcol]);
        nv[j] = *reinterpret_cast<const short8*>(&VTh[(size_t)(vrow0 + 16 * j) * Tq + nx + vcol]);
      }
    }

    // two 64-kv halves
    #pragma unroll
    for (int h2 = 0; h2 < 2; ++h2) {
      const int kvb = kv0 + h2 * 64;

      // S^T = K · Q^T (already exp2-domain via pre-scaled Q)
      f32x4 sarr[4];
      __builtin_amdgcn_s_setprio(1);
      #pragma unroll
      for (int nb = 0; nb < 4; ++nb) {
        f32x4 a = {};
        #pragma unroll
        for (int kk = 0; kk < 2; ++kk) {
          short8 kf = *reinterpret_cast<const short8*>(
              &Ks[h2 * 64 + nb * 16 + li][kk * 32 + 8 * g]);
          a = __builtin_amdgcn_mfma_f32_16x16x32_bf16(kf, qf[kk], a, 0, 0, 0);
        }
        sarr[nb] = a;
      }
      __builtin_amdgcn_s_setprio(0);

      // mask + direct exp2 (no offset: o/l invariant to constant scaling)
      const bool needmask = !((kvb + 63 <= q0 + w * 16) || (kvb + 63 < nf));
      float p[4][4];
      #pragma unroll
      for (int nb = 0; nb < 4; ++nb) {
        #pragma unroll
        for (int r = 0; r < 4; ++r) {
          float v = sarr[nb][r];
          if (needmask) {
            const int kvi = kvb + nb * 16 + 4 * g + r;
            if (!(kvi <= qrow || kvi < nf)) v = -1e30f;
          }
          p[nb][r] = exp2f(v);
        }
      }

      // pack + permlane 4x4 word transpose -> PV B-fragments; PV MFMA
      #pragma unroll
      for (int kk = 0; kk < 2; ++kk) {
        unsigned int X1 = cvtpk_bf16(p[2 * kk][0], p[2 * kk][1]);
        unsigned int X2 = cvtpk_bf16(p[2 * kk][2], p[2 * kk][3]);
        unsigned int Y1 = cvtpk_bf16(p[2 * kk + 1][0], p[2 * kk + 1][1]);
        unsigned int Y2 = cvtpk_bf16(p[2 * kk + 1][2], p[2 * kk + 1][3]);
        asm volatile("v_permlane32_swap_b32 %0, %1" : "+v"(X1), "+v"(Y1));
        asm volatile("v_permlane32_swap_b32 %0, %1" : "+v"(X2), "+v"(Y2));
        asm volatile("v_permlane16_swap_b32 %0, %1" : "+v"(X1), "+v"(Y1));
        asm volatile("v_permlane16_swap_b32 %0, %1" : "+v"(X2), "+v"(Y2));
        union { unsigned int u[4]; short8 s8; } W;
        W.u[0] = X1; W.u[1] = X2; W.u[2] = Y1; W.u[3] = Y2;
        __builtin_amdgcn_s_setprio(1);
        #pragma unroll
        for (int db = 0; db < 4; ++db) {
          short8 vb = *reinterpret_cast<const short8*>(
              &VTs[db * 16 + li][h2 * 64 + kk * 32 + 8 * g]);
          o[db] = __builtin_amdgcn_mfma_f32_16x16x32_bf16(vb, W.s8, o[db], 0, 0, 0);
        }
        ol = __builtin_amdgcn_mfma_f32_16x16x32_bf16(ones, W.s8, ol, 0, 0, 0);
        __builtin_amdgcn_s_setprio(0);
      }
    }

    if (havenext) {
      __syncthreads();   // all waves done reading current tile
      #pragma unroll
      for (int j = 0; j < 4; ++j) {
        *reinterpret_cast<short8*>(&Ks[krow0 + 32 * j][kcol]) = nk[j];
        *reinterpret_cast<short8*>(&VTs[vrow0 + 16 * j][vcol]) = nv[j];
      }
      __syncthreads();   // new tile visible
    }
  }

  // epilogue: write UNNORMALIZED partial O (bf16) + partial l (f32)
  unsigned short* pp = (s == 2 ? po2 : po01 + (size_t)s * NH * Tq * DH)
                       + ((size_t)h * Tq + qrow) * DH;
  #pragma unroll
  for (int db = 0; db < 4; ++db) {
    ushort4 pk;
    pk.x = f2bf(o[db][0]);
    pk.y = f2bf(o[db][1]);
    pk.z = f2bf(o[db][2]);
    pk.w = f2bf(o[db][3]);
    *reinterpret_cast<ushort4*>(&pp[db * 16 + 4 * g]) = pk;
  }
  if (g == 0)
    pl[((size_t)s * NH + h) * Tq + qrow] = ol[0];
}

// ------------- merge split partials: ybf = (po0+po1+po2)/(l0+l1+l2) -------------
__global__ __launch_bounds__(256)
void merge_kernel(const unsigned short* __restrict__ po01,  // [2][16][4096][64] bf16
                  const unsigned short* __restrict__ po2,   // [16][4096][64] bf16
                  const float* __restrict__ pl,             // [3][16][4096] f32
                  unsigned short* __restrict__ ybf)         // [4096][1024] bf16
{
  const int idx = blockIdx.x * 256 + threadIdx.x;  // 524288 total (one per 8 d-elems)
  const int d8  = idx & 7;
  const int row = (idx >> 3) & 4095;
  const int h   = idx >> 15;
  const size_t base = ((size_t)h * Tq + row) * DH + d8 * 8;
  short8 a = *reinterpret_cast<const short8*>(&po01[base]);
  short8 b = *reinterpret_cast<const short8*>(&po01[(size_t)NH * Tq * DH + base]);
  short8 c = *reinterpret_cast<const short8*>(&po2[base]);
  const float l0 = pl[(size_t)h * Tq + row];
  const float l1 = pl[((size_t)NH + h) * Tq + row];
  const float l2 = pl[((size_t)2 * NH + h) * Tq + row];
  const float inv = 1.0f / (l0 + l1 + l2);
  short8 outv;
  #pragma unroll
  for (int j = 0; j < 8; ++j) {
    float v = (bf2f((unsigned short)a[j]) + bf2f((unsigned short)b[j])
               + bf2f((unsigned short)c[j])) * inv;
    outv[j] = (short)f2bf(v);
  }
  *reinterpret_cast<short8*>(&ybf[(size_t)row * Cdim + h * DH + d8 * 8]) = outv;
}

extern "C" void kernel_launch(void* const* d_in, const int* in_sizes, int n_in,
                              void* d_out, int out_size, void* d_ws, size_t ws_size,
                              hipStream_t stream) {
  (void)in_sizes; (void)n_in; (void)out_size; (void)ws_size;
  const float* x  = (const float*)d_in[0];
  const float* wa = (const float*)d_in[1];
  const float* wp = (const float*)d_in[2];
  const int*   nf = (const int*)d_in[3];
  float* out = (float*)d_out;

  char* ws = (char*)d_ws;
  unsigned short* x_bf = (unsigned short*)(ws);                              // 8 MiB (dead after gemm<0>)
  unsigned short* waT  = (unsigned short*)(ws + (size_t)8  * 1024 * 1024);   // 6 MiB (dead after gemm<0>)
  unsigned short* wpT  = (unsigned short*)(ws + (size_t)14 * 1024 * 1024);   // 2 MiB
  unsigned short* qkvb = (unsigned short*)(ws + (size_t)16 * 1024 * 1024);   // 24 MiB
  unsigned short* ybf  = (unsigned short*)(ws + (size_t)40 * 1024 * 1024);   // 8 MiB

  // split-K partials: po0/po1 in d_out (16 MiB, fully rewritten by gemm<1>);
  // pl (768 KiB) at ws+0 and po2 (8 MiB) at ws+1MiB, overlaying the dead
  // x_bf/waT regions (attn runs strictly after gemm<0>).
  unsigned short* po01 = (unsigned short*)d_out;
  float* pl = (float*)(ws);
  unsigned short* po2 = (unsigned short*)(ws + (size_t)1 * 1024 * 1024);

  cvt_kernel<<<4096, 256, 0, stream>>>(x, x_bf, Tq * Cdim);
  transpose_cvt<<<dim3(48, 16), 256, 0, stream>>>(wa, waT, 1024, 3072);
  transpose_cvt<<<dim3(16, 16), 256, 0, stream>>>(wp, wpT, 1024, 1024);
  gemm_bt<0><<<768, 256, 0, stream>>>(x_bf, waT, (void*)qkvb, Tq, 3 * Cdim, Cdim);
  attn_kernel<<<3072, 256, 0, stream>>>(qkvb, po01, po2, pl, nf);
  merge_kernel<<<2048, 256, 0, stream>>>(po01, po2, pl, ybf);
  gemm_bt<1><<<256, 256, 0, stream>>>(ybf, wpT, (void*)out, Tq, Cdim, Cdim);
}

// Round 18
// 148.452 us; speedup vs baseline: 1.4467x; 1.0092x over previous
//
#include <hip/hip_runtime.h>
#include <hip/hip_bf16.h>

#define Tq 4096
#define Cdim 1024
#define NH 16
#define DH 64

typedef __attribute__((ext_vector_type(8))) short short8;
typedef __attribute__((ext_vector_type(4))) float f32x4;

#define SCLQ 0.1803368801111204f   // (1/sqrt(64)) * log2(e), folded into Q

__device__ __forceinline__ unsigned short f2bf(float f) {
  union { float f; unsigned int u; } v; v.f = f;
  unsigned int r = v.u + 0x7FFFu + ((v.u >> 16) & 1u);
  return (unsigned short)(r >> 16);
}

__device__ __forceinline__ float bf2f(unsigned short u) {
  union { unsigned int u; float f; } v; v.u = ((unsigned int)u) << 16;
  return v.f;
}

__device__ __forceinline__ unsigned int cvtpk_bf16(float lo, float hi) {
  unsigned int r;
  asm volatile("v_cvt_pk_bf16_f32 %0, %1, %2" : "=v"(r) : "v"(lo), "v"(hi));
  return r;
}

// ---------------- fp32 -> bf16 convert ----------------
__global__ void cvt_kernel(const float* __restrict__ in, unsigned short* __restrict__ out, int n) {
  int idx = (blockIdx.x * blockDim.x + threadIdx.x) * 4;
  if (idx + 3 < n) {
    float4 v = *reinterpret_cast<const float4*>(in + idx);
    ushort4 o;
    o.x = f2bf(v.x); o.y = f2bf(v.y); o.z = f2bf(v.z); o.w = f2bf(v.w);
    *reinterpret_cast<ushort4*>(out + idx) = o;
  }
}

// ------------- transpose + convert: in[R][C] f32 -> out[C][R] bf16 -------------
__global__ void transpose_cvt(const float* __restrict__ in, unsigned short* __restrict__ out,
                              int R, int Ccols) {
  __shared__ float tile[64][65];
  int c0 = blockIdx.x * 64, r0 = blockIdx.y * 64;
  int tx = threadIdx.x & 63;
  int ty = threadIdx.x >> 6;   // 0..3
  #pragma unroll
  for (int rr = 0; rr < 64; rr += 4)
    tile[rr + ty][tx] = in[(r0 + rr + ty) * Ccols + c0 + tx];
  __syncthreads();
  #pragma unroll
  for (int rr = 0; rr < 64; rr += 4)
    out[(c0 + rr + ty) * R + r0 + tx] = f2bf(tile[tx][rr + ty]);
}

// ------------- GEMM: C[M][N] = A[M][K](bf16) * B^T[N][K](bf16) -------------
// m97 structure: linear LDS + global_load_lds width-16, 2 barriers/K-step.
// OUT_MODE 0 pre-scales the Q section by SCLQ (softmax fold).
// BNT: N-tile size (128 for gemm<0>; 64 for gemm<1> so grid 512 = 2 blocks/CU
// instead of 256 = 1 block/CU -- m114: barrier drains need co-resident blocks).
template<int OUT_MODE, int BNT>
__global__ __launch_bounds__(256, 3)
void gemm_bt(const unsigned short* __restrict__ A,
             const unsigned short* __restrict__ B,
             void* __restrict__ Cout,
             int M, int N, int K)
{
  __shared__ __align__(16) unsigned short As[128][64];
  __shared__ __align__(16) unsigned short Bs[BNT][64];
  const int tid = threadIdx.x;
  const int lane = tid & 63;
  const int wave = tid >> 6;
  const int wm = wave >> 1, wn = wave & 1;
  constexpr int NJ = BNT >> 5;          // j-iterations per wave (4 for 128, 2 for 64)

  // XCD swizzle (gridDim.x % 8 == 0 guaranteed by launch config)
  const int chunk = gridDim.x >> 3;
  const int b = blockIdx.x;
  const int swz = (b & 7) * chunk + (b >> 3);
  const int n0 = (swz >> 5) * BNT;   // 32 M-blocks per column panel (M=4096)
  const int m0 = (swz & 31) * 128;

  f32x4 acc[4][NJ] = {};

  const int lrow = lane >> 3;        // 0..7 (row within one 1KB wave deposit)
  const int lcol = (lane & 7) * 8;   // ushort col within 64

  for (int k0 = 0; k0 < K; k0 += 64) {
    __syncthreads();
    #pragma unroll
    for (int t = 0; t < 4; ++t) {
      const int r = wave * 32 + t * 8;
      __builtin_amdgcn_global_load_lds(
        (const __attribute__((address_space(1))) void*)&A[(size_t)(m0 + r + lrow) * K + k0 + lcol],
        (__attribute__((address_space(3))) void*)&As[r][0], 16, 0, 0);
    }
    #pragma unroll
    for (int t = 0; t < BNT / 32; ++t) {
      const int r = wave * (BNT / 4) + t * 8;
      __builtin_amdgcn_global_load_lds(
        (const __attribute__((address_space(1))) void*)&B[(size_t)(n0 + r + lrow) * K + k0 + lcol],
        (__attribute__((address_space(3))) void*)&Bs[r][0], 16, 0, 0);
    }
    __syncthreads();
    #pragma unroll
    for (int kk = 0; kk < 64; kk += 32) {
      const int frow = lane & 15;
      const int fcol = kk + 8 * (lane >> 4);
      short8 a[4], bfr[NJ];
      #pragma unroll
      for (int i = 0; i < 4; ++i)
        a[i] = *reinterpret_cast<const short8*>(&As[wm * 64 + i * 16 + frow][fcol]);
      #pragma unroll
      for (int j = 0; j < NJ; ++j)
        bfr[j] = *reinterpret_cast<const short8*>(&Bs[wn * (BNT / 2) + j * 16 + frow][fcol]);
      #pragma unroll
      for (int i = 0; i < 4; ++i)
        #pragma unroll
        for (int j = 0; j < NJ; ++j)
          acc[i][j] = __builtin_amdgcn_mfma_f32_16x16x32_bf16(a[i], bfr[j], acc[i][j], 0, 0, 0);
    }
  }

  const int rbase = (lane >> 4) * 4;
  const int ccol = lane & 15;
  #pragma unroll
  for (int i = 0; i < 4; ++i) {
    const int row0 = m0 + wm * 64 + i * 16 + rbase;
    #pragma unroll
    for (int j = 0; j < NJ; ++j) {
      const int col = n0 + wn * (BNT / 2) + j * 16 + ccol;
      if (OUT_MODE == 0) {
        unsigned short* q = (unsigned short*)Cout;
        int sec = col >> 10, rem = col & 1023;
        int hh = rem >> 6, d = rem & 63;
        if (sec == 2) {
          ushort4 pk;
          pk.x = f2bf(acc[i][j][0]); pk.y = f2bf(acc[i][j][1]);
          pk.z = f2bf(acc[i][j][2]); pk.w = f2bf(acc[i][j][3]);
          *reinterpret_cast<ushort4*>(
              &q[((size_t)(2 * NH + hh) * DH + d) * Tq + row0]) = pk;
        } else {
          const float mult = (sec == 0) ? SCLQ : 1.0f;   // fold softmax scale into Q
          #pragma unroll
          for (int r = 0; r < 4; ++r)
            q[(((size_t)sec * NH + hh) * Tq + row0 + r) * DH + d] = f2bf(acc[i][j][r] * mult);
        }
      } else {
        #pragma unroll
        for (int r = 0; r < 4; ++r)
          ((float*)Cout)[(row0 + r) * N + col] = acc[i][j][r];
      }
    }
  }
}

// ------------- flash attention, KV split-K=3: causal + dense prefix -------------
// QBLK=64, 4 waves x 16 q-rows, 256 threads. Split s takes kv-tiles t = s, s+3, ...
// Q pre-scaled -> p = exp2(s) directly. LDS strides 72/136 ushorts
// (36/68 dwords == 4 mod 32: the b128-optimal 16B-slot spread). This
// 4-block/CU, 52-VGPR config sits on the HW quanta: zero-LDS (r13),
// 64kv/8-block (r14), and shared-fragment QBLK=128 (r16) all falsified
// with spill/latency counter evidence.
__global__ __launch_bounds__(256, 4)
void attn_kernel(const unsigned short* __restrict__ qkv,   // Q[h][t][d],K[h][t][d],VT[h][d][t]
                 unsigned short* __restrict__ po01,        // [2][16][4096][64] bf16 (d_out)
                 unsigned short* __restrict__ po2,         // [16][4096][64] bf16 (ws)
                 float* __restrict__ pl,                   // [3][16][4096] f32
                 const int* __restrict__ nf_ptr)
{
  __shared__ __align__(16) unsigned short Ks[128][72];
  __shared__ __align__(16) unsigned short VTs[64][136];

  const int tid  = threadIdx.x;
  const int lane = tid & 63;
  const int w    = tid >> 6;           // 0..3
  const int g    = lane >> 4;          // 0..3
  const int li   = lane & 15;

  // grid 3072: h = b&15; s = (b>>4)%3; qc = 63 - (b>>4)/3  (heavy-first LPT)
  const int h   = blockIdx.x & 15;
  const int bb  = blockIdx.x >> 4;
  const int s   = bb % 3;
  const int qc  = 63 - bb / 3;
  const int q0  = qc * 64;
  const int nf  = nf_ptr[0];

  const unsigned short* Qh  = qkv + (size_t)h * Tq * DH;
  const unsigned short* Kh  = qkv + (size_t)(NH + h) * Tq * DH;
  const unsigned short* VTh = qkv + (size_t)(2 * NH + h) * DH * Tq;

  // Q fragments (B-operand of swapped QK^T): col = li = q-row
  const int qrow = q0 + w * 16 + li;
  short8 qf[2];
  #pragma unroll
  for (int kk = 0; kk < 2; ++kk)
    qf[kk] = *reinterpret_cast<const short8*>(&Qh[qrow * DH + kk * 32 + 8 * g]);

  f32x4 o[4] = {};
  f32x4 ol = {};

  short8 ones;
  #pragma unroll
  for (int e = 0; e < 8; ++e) ones[e] = (short)0x3F80;   // bf16 1.0

  int lastt = q0 + 63;
  if (nf - 1 > lastt) lastt = nf - 1;
  const int T = (lastt >> 7) + 1;      // number of 128-wide KV tiles for this chunk

  // staging thread mapping (256 threads, 4 segs each for K and VT)
  const int krow0 = tid >> 3;           // 0..31 (+32j)
  const int kcol  = (tid & 7) * 8;
  const int vrow0 = tid >> 4;           // 0..15 (+16j)
  const int vcol  = (tid & 15) * 8;

  // prologue: stage this split's first tile (kv = s*128; within bounds for all s)
  {
    const int nx = s * 128;
    short8 nk[4], nv[4];
    #pragma unroll
    for (int j = 0; j < 4; ++j) {
      nk[j] = *reinterpret_cast<const short8*>(&Kh[(nx + krow0 + 32 * j) * DH + kcol]);
      nv[j] = *reinterpret_cast<const short8*>(&VTh[(size_t)(vrow0 + 16 * j) * Tq + nx + vcol]);
    }
    #pragma unroll
    for (int j = 0; j < 4; ++j) {
      *reinterpret_cast<short8*>(&Ks[krow0 + 32 * j][kcol]) = nk[j];
      *reinterpret_cast<short8*>(&VTs[vrow0 + 16 * j][vcol]) = nv[j];
    }
  }
  __syncthreads();

  for (int t = s; t < T; t += 3) {
    const int kv0 = t * 128;
    const bool havenext = (t + 3 < T);
    // T14: issue next tile's global loads now; they fly during compute
    short8 nk[4], nv[4];
    if (havenext) {
      const int nx = kv0 + 384;
      #pragma unroll
      for (int j = 0; j < 4; ++j) {
        nk[j] = *reinterpret_cast<const short8*>(&Kh[(nx + krow0 + 32 * j) * DH + kcol]);
        nv[j] = *reinterpret_cast<const short8*>(&VTh[(size_t)(vrow0 + 16 * j) * Tq + nx + vcol]);
      }
    }

    // two 64-kv halves
    #pragma unroll
    for (int h2 = 0; h2 < 2; ++h2) {
      const int kvb = kv0 + h2 * 64;

      // S^T = K · Q^T (already exp2-domain via pre-scaled Q)
      f32x4 sarr[4];
      __builtin_amdgcn_s_setprio(1);
      #pragma unroll
      for (int nb = 0; nb < 4; ++nb) {
        f32x4 a = {};
        #pragma unroll
        for (int kk = 0; kk < 2; ++kk) {
          short8 kf = *reinterpret_cast<const short8*>(
              &Ks[h2 * 64 + nb * 16 + li][kk * 32 + 8 * g]);
          a = __builtin_amdgcn_mfma_f32_16x16x32_bf16(kf, qf[kk], a, 0, 0, 0);
        }
        sarr[nb] = a;
      }
      __builtin_amdgcn_s_setprio(0);

      // mask + direct exp2 (no offset: o/l invariant to constant scaling)
      const bool needmask = !((kvb + 63 <= q0 + w * 16) || (kvb + 63 < nf));
      float p[4][4];
      #pragma unroll
      for (int nb = 0; nb < 4; ++nb) {
        #pragma unroll
        for (int r = 0; r < 4; ++r) {
          float v = sarr[nb][r];
          if (needmask) {
            const int kvi = kvb + nb * 16 + 4 * g + r;
            if (!(kvi <= qrow || kvi < nf)) v = -1e30f;
          }
          p[nb][r] = exp2f(v);
        }
      }

      // pack + permlane 4x4 word transpose -> PV B-fragments; PV MFMA
      #pragma unroll
      for (int kk = 0; kk < 2; ++kk) {
        unsigned int X1 = cvtpk_bf16(p[2 * kk][0], p[2 * kk][1]);
        unsigned int X2 = cvtpk_bf16(p[2 * kk][2], p[2 * kk][3]);
        unsigned int Y1 = cvtpk_bf16(p[2 * kk + 1][0], p[2 * kk + 1][1]);
        unsigned int Y2 = cvtpk_bf16(p[2 * kk + 1][2], p[2 * kk + 1][3]);
        asm volatile("v_permlane32_swap_b32 %0, %1" : "+v"(X1), "+v"(Y1));
        asm volatile("v_permlane32_swap_b32 %0, %1" : "+v"(X2), "+v"(Y2));
        asm volatile("v_permlane16_swap_b32 %0, %1" : "+v"(X1), "+v"(Y1));
        asm volatile("v_permlane16_swap_b32 %0, %1" : "+v"(X2), "+v"(Y2));
        union { unsigned int u[4]; short8 s8; } W;
        W.u[0] = X1; W.u[1] = X2; W.u[2] = Y1; W.u[3] = Y2;
        __builtin_amdgcn_s_setprio(1);
        #pragma unroll
        for (int db = 0; db < 4; ++db) {
          short8 vb = *reinterpret_cast<const short8*>(
              &VTs[db * 16 + li][h2 * 64 + kk * 32 + 8 * g]);
          o[db] = __builtin_amdgcn_mfma_f32_16x16x32_bf16(vb, W.s8, o[db], 0, 0, 0);
        }
        ol = __builtin_amdgcn_mfma_f32_16x16x32_bf16(ones, W.s8, ol, 0, 0, 0);
        __builtin_amdgcn_s_setprio(0);
      }
    }

    if (havenext) {
      __syncthreads();   // all waves done reading current tile
      #pragma unroll
      for (int j = 0; j < 4; ++j) {
        *reinterpret_cast<short8*>(&Ks[krow0 + 32 * j][kcol]) = nk[j];
        *reinterpret_cast<short8*>(&VTs[vrow0 + 16 * j][vcol]) = nv[j];
      }
      __syncthreads();   // new tile visible
    }
  }

  // epilogue: write UNNORMALIZED partial O (bf16) + partial l (f32)
  unsigned short* pp = (s == 2 ? po2 : po01 + (size_t)s * NH * Tq * DH)
                       + ((size_t)h * Tq + qrow) * DH;
  #pragma unroll
  for (int db = 0; db < 4; ++db) {
    ushort4 pk;
    pk.x = f2bf(o[db][0]);
    pk.y = f2bf(o[db][1]);
    pk.z = f2bf(o[db][2]);
    pk.w = f2bf(o[db][3]);
    *reinterpret_cast<ushort4*>(&pp[db * 16 + 4 * g]) = pk;
  }
  if (g == 0)
    pl[((size_t)s * NH + h) * Tq + qrow] = ol[0];
}

// ------------- merge split partials: ybf = (po0+po1+po2)/(l0+l1+l2) -------------
__global__ __launch_bounds__(256)
void merge_kernel(const unsigned short* __restrict__ po01,  // [2][16][4096][64] bf16
                  const unsigned short* __restrict__ po2,   // [16][4096][64] bf16
                  const float* __restrict__ pl,             // [3][16][4096] f32
                  unsigned short* __restrict__ ybf)         // [4096][1024] bf16
{
  const int idx = blockIdx.x * 256 + threadIdx.x;  // 524288 total (one per 8 d-elems)
  const int d8  = idx & 7;
  const int row = (idx >> 3) & 4095;
  const int h   = idx >> 15;
  const size_t base = ((size_t)h * Tq + row) * DH + d8 * 8;
  short8 a = *reinterpret_cast<const short8*>(&po01[base]);
  short8 b = *reinterpret_cast<const short8*>(&po01[(size_t)NH * Tq * DH + base]);
  short8 c = *reinterpret_cast<const short8*>(&po2[base]);
  const float l0 = pl[(size_t)h * Tq + row];
  const float l1 = pl[((size_t)NH + h) * Tq + row];
  const float l2 = pl[((size_t)2 * NH + h) * Tq + row];
  const float inv = 1.0f / (l0 + l1 + l2);
  short8 outv;
  #pragma unroll
  for (int j = 0; j < 8; ++j) {
    float v = (bf2f((unsigned short)a[j]) + bf2f((unsigned short)b[j])
               + bf2f((unsigned short)c[j])) * inv;
    outv[j] = (short)f2bf(v);
  }
  *reinterpret_cast<short8*>(&ybf[(size_t)row * Cdim + h * DH + d8 * 8]) = outv;
}

extern "C" void kernel_launch(void* const* d_in, const int* in_sizes, int n_in,
                              void* d_out, int out_size, void* d_ws, size_t ws_size,
                              hipStream_t stream) {
  (void)in_sizes; (void)n_in; (void)out_size; (void)ws_size;
  const float* x  = (const float*)d_in[0];
  const float* wa = (const float*)d_in[1];
  const float* wp = (const float*)d_in[2];
  const int*   nf = (const int*)d_in[3];
  float* out = (float*)d_out;

  char* ws = (char*)d_ws;
  unsigned short* x_bf = (unsigned short*)(ws);                              // 8 MiB (dead after gemm<0>)
  unsigned short* waT  = (unsigned short*)(ws + (size_t)8  * 1024 * 1024);   // 6 MiB (dead after gemm<0>)
  unsigned short* wpT  = (unsigned short*)(ws + (size_t)14 * 1024 * 1024);   // 2 MiB
  unsigned short* qkvb = (unsigned short*)(ws + (size_t)16 * 1024 * 1024);   // 24 MiB
  unsigned short* ybf  = (unsigned short*)(ws + (size_t)40 * 1024 * 1024);   // 8 MiB

  // split-K partials: po0/po1 in d_out (16 MiB, fully rewritten by gemm<1>);
  // pl (768 KiB) at ws+0 and po2 (8 MiB) at ws+1MiB, overlaying the dead
  // x_bf/waT regions (attn runs strictly after gemm<0>).
  unsigned short* po01 = (unsigned short*)d_out;
  float* pl = (float*)(ws);
  unsigned short* po2 = (unsigned short*)(ws + (size_t)1 * 1024 * 1024);

  cvt_kernel<<<4096, 256, 0, stream>>>(x, x_bf, Tq * Cdim);
  transpose_cvt<<<dim3(48, 16), 256, 0, stream>>>(wa, waT, 1024, 3072);
  transpose_cvt<<<dim3(16, 16), 256, 0, stream>>>(wp, wpT, 1024, 1024);
  gemm_bt<0, 128><<<768, 256, 0, stream>>>(x_bf, waT, (void*)qkvb, Tq, 3 * Cdim, Cdim);
  attn_kernel<<<3072, 256, 0, stream>>>(qkvb, po01, po2, pl, nf);
  merge_kernel<<<2048, 256, 0, stream>>>(po01, po2, pl, ybf);
  gemm_bt<1, 64><<<512, 256, 0, stream>>>(ybf, wpT, (void*)out, Tq, Cdim, Cdim);
}